// Round 1
// baseline (4255.313 us; speedup 1.0000x reference)
//
#include <hip/hip_runtime.h>
#include <math.h>

#define NPTS   200000
#define CR     64
#define CR2    32

// scale segment counts / offsets
#define NSEG0      1382400
#define CNT_OFF1   1382400
#define CNT_OFF2   1555200
#define CNT_OFF3   1612800
#define CNT_TOTAL  1634400
#define SUM123_ROW2 172800   // s2 row offset inside sum123
#define SUM123_ROW3 230400   // s3 row offset inside sum123
#define SUM123_ROWS 252000   // total rows in sum123 (s1+s2+s3)

#define TVSEG  1382400       // B*GZ2*GY2*GX2 = 2*16*180*240
#define GX2    240
#define GY2    180
#define GZ2    16

__device__ __forceinline__ int lin_scale(int b, int x, int y, int z,
                                         int ps, int dx, int dy, int dz) {
    int qx = x / ps, qy = y / ps, qz = z / ps;
    return ((b * dx + qx) * dy + qy) * dz + qz;
}

// ---------------- K1: reduced = relu(input @ W_red + b_red) ----------------
__global__ __launch_bounds__(256) void k_reduced(
        const float* __restrict__ in, const float* __restrict__ Wred,
        const float* __restrict__ bred, float* __restrict__ red) {
    __shared__ float Wl[CR * CR];
    __shared__ float bl[CR];
    for (int i = threadIdx.x; i < CR * CR; i += blockDim.x) Wl[i] = Wred[i];
    if (threadIdx.x < CR) bl[threadIdx.x] = bred[threadIdx.x];
    __syncthreads();
    int lane = threadIdx.x & 63;
    int wid  = blockIdx.x * (blockDim.x >> 6) + (threadIdx.x >> 6);
    int nw   = gridDim.x * (blockDim.x >> 6);
    for (int r = wid; r < NPTS; r += nw) {
        float x = in[r * CR + lane];
        float acc = bl[lane];
#pragma unroll
        for (int k = 0; k < CR; ++k)
            acc += __shfl(x, k, 64) * Wl[k * CR + lane];
        red[r * CR + lane] = fmaxf(acc, 0.f);
    }
}

// ---------------- K2: scatter-add segment sums + counts ----------------
__global__ __launch_bounds__(256) void k_scatter(
        const float* __restrict__ red, const int* __restrict__ coords,
        float* __restrict__ sum0, float* __restrict__ sum123,
        float* __restrict__ cnt) {
    int lane = threadIdx.x & 63;
    int wid  = blockIdx.x * (blockDim.x >> 6) + (threadIdx.x >> 6);
    int nw   = gridDim.x * (blockDim.x >> 6);
    for (int r = wid; r < NPTS; r += nw) {
        int cb = coords[4 * r + 0], cx = coords[4 * r + 1];
        int cy = coords[4 * r + 2], cz = coords[4 * r + 3];
        int l0 = lin_scale(cb, cx, cy, cz, 2, 240, 180, 16);
        int l1 = lin_scale(cb, cx, cy, cz, 4, 120,  90,  8);
        int l2 = lin_scale(cb, cx, cy, cz, 6,  80,  60,  6);
        int l3 = lin_scale(cb, cx, cy, cz, 8,  60,  45,  4);
        float v = red[r * CR + lane];
        atomicAdd(&sum0[(size_t)l0 * CR + lane], v);
        atomicAdd(&sum123[(size_t)l1 * CR + lane], v);
        atomicAdd(&sum123[(size_t)(SUM123_ROW2 + l2) * CR + lane], v);
        atomicAdd(&sum123[(size_t)(SUM123_ROW3 + l3) * CR + lane], v);
        if (lane < 4) {
            int myLin, myOff;
            if (lane == 0)      { myLin = l0; myOff = 0; }
            else if (lane == 1) { myLin = l1; myOff = CNT_OFF1; }
            else if (lane == 2) { myLin = l2; myOff = CNT_OFF2; }
            else                { myLin = l3; myOff = CNT_OFF3; }
            atomicAdd(&cnt[myOff + myLin], 1.0f);
        }
    }
}

// ---------------- K3: fused per-point chain -> proj0 ----------------
__global__ __launch_bounds__(256) void k_point(
        const float* __restrict__ red,
        const float* __restrict__ sum0, const float* __restrict__ sum123,
        const float* __restrict__ cnt, const int* __restrict__ coords,
        const float* __restrict__ fcW, const float* __restrict__ fcB,
        const float* __restrict__ fcsW, const float* __restrict__ fcsB,
        const float* __restrict__ fc_W, const float* __restrict__ outW,
        const float* __restrict__ loW1, const float* __restrict__ loW2,
        const float* __restrict__ lob2, float* __restrict__ proj0) {
    int lane = threadIdx.x & 63;
    int d = lane & 31;
    int h = lane >> 5;
    int wid  = blockIdx.x * (blockDim.x >> 6) + (threadIdx.x >> 6);
    int nw   = gridDim.x * (blockDim.x >> 6);
    const float* WA = fcW + (h ? 1 : 0) * CR * CR2;
    const float* WB = fcW + (h ? 3 : 2) * CR * CR2;
    const float* VA = fcsW + (h ? 1 : 0) * CR2 * CR2;
    const float* VB = fcsW + (h ? 3 : 2) * CR2 * CR2;
    float biasA = fcB[(h ? 1 : 0) * CR2 + d];
    float biasB = fcB[(h ? 3 : 2) * CR2 + d];
    float vbA = fcsB[(h ? 1 : 0) * CR2 + d];
    float vbB = fcsB[(h ? 3 : 2) * CR2 + d];
    float lob = lob2[lane];

    for (int r = wid; r < NPTS; r += nw) {
        int cb = coords[4 * r + 0], cx = coords[4 * r + 1];
        int cy = coords[4 * r + 2], cz = coords[4 * r + 3];
        int l0 = lin_scale(cb, cx, cy, cz, 2, 240, 180, 16);
        int l1 = lin_scale(cb, cx, cy, cz, 4, 120,  90,  8);
        int l2 = lin_scale(cb, cx, cy, cz, 6,  80,  60,  6);
        int l3 = lin_scale(cb, cx, cy, cz, 8,  60,  45,  4);
        float xr = red[r * CR + lane];
        float m0 = sum0[(size_t)l0 * CR + lane] / fmaxf(cnt[l0], 1.f);
        float m1 = sum123[(size_t)l1 * CR + lane] / fmaxf(cnt[CNT_OFF1 + l1], 1.f);
        float m2 = sum123[(size_t)(SUM123_ROW2 + l2) * CR + lane] / fmaxf(cnt[CNT_OFF2 + l2], 1.f);
        float m3 = sum123[(size_t)(SUM123_ROW3 + l3) * CR + lane] / fmaxf(cnt[CNT_OFF3 + l3], 1.f);

        // att for 4 scales: lanes 0-31 do scales {0,2}, lanes 32-63 do {1,3}
        float accA = biasA, accB = biasB;
#pragma unroll
        for (int k = 0; k < CR; ++k) {
            float a0 = __shfl(m0, k, 64), a1 = __shfl(m1, k, 64);
            float a2 = __shfl(m2, k, 64), a3 = __shfl(m3, k, 64);
            accA += (h ? a1 : a0) * WA[k * CR2 + d];
            accB += (h ? a3 : a2) * WB[k * CR2 + d];
        }
        float sfA = fmaxf(accA, 0.f);   // sf[scale h][d]
        float sfB = fmaxf(accB, 0.f);   // sf[scale 2+h][d]

        // featS replicated across halves
        float t = sfA + sfB;
        float featS = t + __shfl_xor(t, 32, 64);

        // featZ = relu(featS @ fc_W)
        float az = 0.f;
#pragma unroll
        for (int c = 0; c < CR2; ++c)
            az += __shfl(featS, c, 64) * fc_W[c * CR2 + d];
        float featZ = fmaxf(az, 0.f);

        // att_v (sigmoid), k = h and 2+h per half
        float avA = vbA, avB = vbB;
#pragma unroll
        for (int c = 0; c < CR2; ++c) {
            float fz = __shfl(featZ, c, 64);
            avA += fz * VA[c * CR2 + d];
            avB += fz * VB[c * CR2 + d];
        }
        avA = 1.f / (1.f + expf(-avA));
        avB = 1.f / (1.f + expf(-avB));

        // fusedIn[d] = sum_k sf_k[d]*attv_k[d], replicated
        float u = sfA * avA + sfB * avB;
        float fI = u + __shfl_xor(u, 32, 64);

        // fused[c] = fusedIn @ out_fc_W  (c = lane, 64 wide)
        float fu = 0.f;
#pragma unroll
        for (int dd = 0; dd < CR2; ++dd)
            fu += __shfl(fI, dd, 64) * outW[dd * CR + lane];

        // h = relu([reduced, fused] @ lo_W1)
        float hh = 0.f;
#pragma unroll
        for (int k = 0; k < CR; ++k)
            hh += __shfl(xr, k, 64) * loW1[k * CR + lane];
#pragma unroll
        for (int k = 0; k < CR; ++k)
            hh += __shfl(fu, k, 64) * loW1[(CR + k) * CR + lane];
        hh = fmaxf(hh, 0.f);

        // proj = h @ lo_W2 + lo_b2
        float pj = lob;
#pragma unroll
        for (int k = 0; k < CR; ++k)
            pj += __shfl(hh, k, 64) * loW2[k * CR + lane];

        proj0[r * CR + lane] = pj;
    }
}

// orderable-uint encoding for float max
__device__ __forceinline__ unsigned int fkey(float f) {
    unsigned int b = __float_as_uint(f);
    return (b & 0x80000000u) ? ~b : (b | 0x80000000u);
}

// ---------------- K4: gather proj, write lin2, scatter tv keys ----------------
__global__ __launch_bounds__(256) void k_gather(
        const float* __restrict__ proj0, const int* __restrict__ inv,
        const int* __restrict__ bxyz, float* __restrict__ outProj,
        float* __restrict__ outLin, unsigned int* __restrict__ tvKey) {
    int lane = threadIdx.x & 63;
    int wid  = blockIdx.x * (blockDim.x >> 6) + (threadIdx.x >> 6);
    int nw   = gridDim.x * (blockDim.x >> 6);
    for (int i = wid; i < NPTS; i += nw) {
        int src = inv[i];
        float v = proj0[(size_t)src * CR + lane];
        outProj[(size_t)i * CR + lane] = v;
        int b = bxyz[4 * i + 0], x = bxyz[4 * i + 1];
        int y = bxyz[4 * i + 2], z = bxyz[4 * i + 3];
        int lin2 = ((b * GZ2 + z) * GY2 + y) * GX2 + x;
        if (lane == 0) outLin[i] = (float)lin2;
        atomicMax(&tvKey[(size_t)lin2 * CR + lane], fkey(v));
    }
}

// ---------------- K5: decode tv keys in place (empty -> 0) ----------------
__global__ __launch_bounds__(256) void k_fix(unsigned int* __restrict__ tv) {
    size_t i = ((size_t)blockIdx.x * blockDim.x + threadIdx.x) * 4;
    if (i >= (size_t)TVSEG * CR) return;
    uint4 k = *(const uint4*)(tv + i);
    float4 f;
    f.x = (k.x == 0u) ? 0.f : __uint_as_float((k.x & 0x80000000u) ? (k.x & 0x7FFFFFFFu) : ~k.x);
    f.y = (k.y == 0u) ? 0.f : __uint_as_float((k.y & 0x80000000u) ? (k.y & 0x7FFFFFFFu) : ~k.y);
    f.z = (k.z == 0u) ? 0.f : __uint_as_float((k.z & 0x80000000u) ? (k.z & 0x7FFFFFFFu) : ~k.z);
    f.w = (k.w == 0u) ? 0.f : __uint_as_float((k.w & 0x80000000u) ? (k.w & 0x7FFFFFFFu) : ~k.w);
    *(float4*)(tv + i) = f;
}

extern "C" void kernel_launch(void* const* d_in, const int* in_sizes, int n_in,
                              void* d_out, int out_size, void* d_ws, size_t ws_size,
                              hipStream_t stream) {
    (void)in_sizes; (void)n_in; (void)out_size; (void)ws_size;
    const float* in_data = (const float*)d_in[0];
    const int*   coords  = (const int*)d_in[1];
    const int*   inv     = (const int*)d_in[2];
    const int*   bxyz    = (const int*)d_in[3];
    const float* W_red   = (const float*)d_in[4];
    const float* b_red   = (const float*)d_in[5];
    const float* fcW     = (const float*)d_in[6];
    const float* fcB     = (const float*)d_in[7];
    const float* fcsW    = (const float*)d_in[8];
    const float* fcsB    = (const float*)d_in[9];
    const float* fc_W    = (const float*)d_in[10];
    const float* outW    = (const float*)d_in[11];
    const float* loW1    = (const float*)d_in[12];
    const float* loW2    = (const float*)d_in[13];
    const float* lob2    = (const float*)d_in[14];

    float* outProj = (float*)d_out;
    float* tv      = outProj + (size_t)NPTS * CR;        // tv_fmap region (also scale-0 sum scratch)
    float* outLin  = tv + (size_t)TVSEG * CR;

    float* ws_f   = (float*)d_ws;
    float* red    = ws_f;                                // N*64
    float* sum123 = red + (size_t)NPTS * CR;             // 252000*64
    float* cnt    = sum123 + (size_t)SUM123_ROWS * CR;   // 1,634,400
    float* proj0  = cnt + (size_t)CNT_TOTAL;             // N*64

    // zero scale-0 sums (in d_out tv region) and ws sums/counts
    hipMemsetAsync(tv, 0, (size_t)TVSEG * CR * sizeof(float), stream);
    hipMemsetAsync(sum123, 0, ((size_t)SUM123_ROWS * CR + CNT_TOTAL) * sizeof(float), stream);

    k_reduced<<<2048, 256, 0, stream>>>(in_data, W_red, b_red, red);
    k_scatter<<<4096, 256, 0, stream>>>(red, coords, tv, sum123, cnt);
    k_point<<<4096, 256, 0, stream>>>(red, tv, sum123, cnt, coords, fcW, fcB, fcsW, fcsB,
                                      fc_W, outW, loW1, loW2, lob2, proj0);

    // reset tv region for atomicMax keys
    hipMemsetAsync(tv, 0, (size_t)TVSEG * CR * sizeof(float), stream);

    k_gather<<<4096, 256, 0, stream>>>(proj0, inv, bxyz, outProj, outLin, (unsigned int*)tv);
    k_fix<<<86400, 256, 0, stream>>>((unsigned int*)tv);
}